// Round 2
// baseline (810.462 us; speedup 1.0000x reference)
//
#include <hip/hip_runtime.h>
#include <hip/hip_bf16.h>

#define NEARZERO 1e-5f

// One thread per grid cell (G=8000). T=730 serial recurrence; all 5 state vars
// in registers. block=64 (one wave) x 125 blocks spreads waves across CUs.
// Inputs/outputs are FLOAT32 (reference uses jax default f32; round-1 NaN was
// the fp32-read-as-bf16 signature).
// 4-step double-buffered register prefetch: issue chunk k+1's loads before
// computing chunk k, so ~12 independent loads are in flight per wave and the
// ~900-cycle HBM latency is covered by ~4 steps of compute.
__global__ __launch_bounds__(64, 1)
void hbv_kernel(const float* __restrict__ x,      // (T, G, 3)
                const float* __restrict__ par,    // (T, G, 14) — only t=T-1 used
                float* __restrict__ out,          // (T, G)
                int T, int G)
{
    const int g = blockIdx.x * 64 + threadIdx.x;
    if (g >= G) return;

    const float lo[14] = {1.0f, 50.0f,   0.05f, 0.01f, 0.001f, 0.2f, 0.0f,  0.0f,   -2.5f, 0.5f,  0.0f, 0.0f, 0.3f, 0.0f};
    const float hi[14] = {6.0f, 1000.0f, 0.9f,  0.5f,  0.2f,   1.0f, 10.0f, 100.0f,  2.5f, 10.0f, 0.1f, 0.2f, 5.0f, 1.0f};

    // phy = sigmoid(parameters[-1, g, :]) scaled to bounds
    const float* p = par + ((size_t)(T - 1) * G + (size_t)g) * 14;
    float ph[14];
#pragma unroll
    for (int i = 0; i < 14; i++) {
        float v = p[i];
        float s = 1.0f / (1.0f + __expf(-v));
        ph[i] = lo[i] + s * (hi[i] - lo[i]);
    }
    const float BETA = ph[0], FC = ph[1], K0 = ph[2], K1 = ph[3], K2 = ph[4],
                LP = ph[5], PERCmax = ph[6], UZL = ph[7], TT = ph[8],
                CFMAX = ph[9], CFR = ph[10], CWH = ph[11], BETAET = ph[12],
                C = ph[13];
    const float invFC    = 1.0f / FC;
    const float invLPFC  = 1.0f / (LP * FC);
    const float CFRCFMAX = CFR * CFMAX;

    float SP = 1e-3f, MW = 1e-3f, SM = 1e-3f, SUZ = 1e-3f, SLZ = 1e-3f;

    const size_t xstride = (size_t)G * 3;
    const float* xbase = x + (size_t)g * 3;
    float* op = out + g;

    constexpr int CH = 4;           // prefetch chunk depth
    float buf[2][CH][3];

    // preload chunk 0 (t = 0..CH-1); T=730 >= CH so no guard needed here
#pragma unroll
    for (int c = 0; c < CH; c++) {
        const float* q = xbase + (size_t)c * xstride;
        buf[0][c][0] = q[0]; buf[0][c][1] = q[1]; buf[0][c][2] = q[2];
    }

    int cur = 0;
    for (int t0 = 0; t0 < T; t0 += CH) {
        // prefetch next chunk (wave-uniform guards -> scalar branches)
        const int nxt = cur ^ 1;
#pragma unroll
        for (int c = 0; c < CH; c++) {
            const int t = t0 + CH + c;
            if (t < T) {
                const float* q = xbase + (size_t)t * xstride;
                buf[nxt][c][0] = q[0]; buf[nxt][c][1] = q[1]; buf[nxt][c][2] = q[2];
            }
        }

#pragma unroll
        for (int c = 0; c < CH; c++) {
            const int t = t0 + c;
            if (t >= T) break;
            const float Pt   = buf[cur][c][0];
            const float Tt   = buf[cur][c][1];
            const float PETt = buf[cur][c][2];

            // snow / melt
            const float is_rain = (Tt >= TT) ? 1.0f : 0.0f;
            const float RAIN = Pt * is_rain;
            const float SNOW = Pt - RAIN;
            SP += SNOW;
            const float melt = fminf(fmaxf(CFMAX * (Tt - TT), 0.0f), SP);
            MW += melt; SP -= melt;
            const float refreeze = fminf(fmaxf(CFRCFMAX * (TT - Tt), 0.0f), MW);
            SP += refreeze; MW -= refreeze;
            const float tosoil = fmaxf(MW - CWH * SP, 0.0f);
            MW -= tosoil;

            // soil moisture: SM >= NEARZERO always, so log2 args are > 0.
            const float sw = fminf(__builtin_amdgcn_exp2f(BETA * __builtin_amdgcn_logf(SM * invFC)), 1.0f);
            const float rt = RAIN + tosoil;
            const float recharge = rt * sw;
            SM += rt - recharge;
            const float excess = fmaxf(SM - FC, 0.0f);
            SM -= excess;
            const float ef = fminf(__builtin_amdgcn_exp2f(BETAET * __builtin_amdgcn_logf(SM * invLPFC)), 1.0f);
            const float ETact = fminf(SM, PETt * ef);
            SM = fmaxf(SM - ETact, NEARZERO);
            const float capillary = fminf(SLZ, C * SLZ * (1.0f - fminf(SM * invFC, 1.0f)));
            SM  = fmaxf(SM + capillary, NEARZERO);
            SLZ = fmaxf(SLZ - capillary, NEARZERO);

            // runoff
            SUZ += recharge + excess;
            const float PERC = fminf(SUZ, PERCmax);
            SUZ -= PERC;
            const float Q0 = K0 * fmaxf(SUZ - UZL, 0.0f);
            SUZ -= Q0;
            const float Q1 = K1 * SUZ;
            SUZ -= Q1;
            SLZ += PERC;
            const float Q2 = K2 * SLZ;
            SLZ -= Q2;

            op[(size_t)t * G] = Q0 + Q1 + Q2;
        }
        cur ^= 1;
    }
}

extern "C" void kernel_launch(void* const* d_in, const int* in_sizes, int n_in,
                              void* d_out, int out_size, void* d_ws, size_t ws_size,
                              hipStream_t stream) {
    const float* x   = (const float*)d_in[0];  // (T, G, 3) f32
    const float* par = (const float*)d_in[1];  // (T, G, 14) f32
    float* out = (float*)d_out;                // (T, G) f32

    const int G = 8000;
    const int T = out_size / G;  // 730

    hbv_kernel<<<dim3((G + 63) / 64), dim3(64), 0, stream>>>(x, par, out, T, G);
}

// Round 3
// 657.172 us; speedup vs baseline: 1.2333x; 1.2333x over previous
//
#include <hip/hip_runtime.h>
#include <hip/hip_bf16.h>

#define NEARZERO 1e-5f

// One thread per grid cell (G=8000), T=730 serial recurrence, state in regs.
// Round-2 post-mortem: VGPR_Count=32 proved the compiler sank the prefetch
// loads to their uses (register-pressure heuristic), serializing one ~900-cyc
// memory latency per step (VALUBusy 2.4%). Fix: CH=8 double-buffered register
// prefetch with an asm memory fence pinning the loads ABOVE the compute block,
// so 24 loads are in flight while ~1000+ cycles of compute retire.
__global__ __launch_bounds__(64, 1)
void hbv_kernel(const float* __restrict__ x,      // (T, G, 3)
                const float* __restrict__ par,    // (T, G, 14) — only t=T-1 used
                float* __restrict__ out,          // (T, G)
                int T, int G)
{
    const int g = blockIdx.x * 64 + threadIdx.x;
    if (g >= G) return;

    const float lo[14] = {1.0f, 50.0f,   0.05f, 0.01f, 0.001f, 0.2f, 0.0f,  0.0f,   -2.5f, 0.5f,  0.0f, 0.0f, 0.3f, 0.0f};
    const float hi[14] = {6.0f, 1000.0f, 0.9f,  0.5f,  0.2f,   1.0f, 10.0f, 100.0f,  2.5f, 10.0f, 0.1f, 0.2f, 5.0f, 1.0f};

    // phy = sigmoid(parameters[-1, g, :]) scaled to bounds
    const float* p = par + ((size_t)(T - 1) * G + (size_t)g) * 14;
    float ph[14];
#pragma unroll
    for (int i = 0; i < 14; i++) {
        float v = p[i];
        float s = 1.0f / (1.0f + __expf(-v));
        ph[i] = lo[i] + s * (hi[i] - lo[i]);
    }
    const float BETA = ph[0], FC = ph[1], K0 = ph[2], K1 = ph[3], K2 = ph[4],
                LP = ph[5], PERCmax = ph[6], UZL = ph[7], TT = ph[8],
                CFMAX = ph[9], CFR = ph[10], CWH = ph[11], BETAET = ph[12],
                C = ph[13];
    const float invFC    = 1.0f / FC;
    const float invLPFC  = 1.0f / (LP * FC);
    const float CFRCFMAX = CFR * CFMAX;

    float SP = 1e-3f, MW = 1e-3f, SM = 1e-3f, SUZ = 1e-3f, SLZ = 1e-3f;

    const size_t xstride = (size_t)G * 3;
    const float* xbase = x + (size_t)g * 3;
    float* op = out + g;

    constexpr int CH = 8;           // prefetch chunk depth (24 loads in flight)
    float buf[2][CH][3];

    // preload chunk 0 (t = 0..CH-1); T=730 >= CH
#pragma unroll
    for (int c = 0; c < CH; c++) {
        const float* q = xbase + (size_t)c * xstride;
        buf[0][c][0] = q[0]; buf[0][c][1] = q[1]; buf[0][c][2] = q[2];
    }

    int cur = 0;
    for (int t0 = 0; t0 < T; t0 += CH) {
        const int nxt = cur ^ 1;

        // ---- prefetch next chunk (issue loads, do NOT consume) ----
        if (t0 + 2 * CH <= T) {                 // full next chunk exists
            const float* q = xbase + (size_t)(t0 + CH) * xstride;
#pragma unroll
            for (int c = 0; c < CH; c++) {
                buf[nxt][c][0] = q[0]; buf[nxt][c][1] = q[1]; buf[nxt][c][2] = q[2];
                q += xstride;
            }
        } else {                                // ragged tail
#pragma unroll
            for (int c = 0; c < CH; c++) {
                const int t = t0 + CH + c;
                if (t < T) {
                    const float* q = xbase + (size_t)t * xstride;
                    buf[nxt][c][0] = q[0]; buf[nxt][c][1] = q[1]; buf[nxt][c][2] = q[2];
                }
            }
        }

        // Fence: forbid the compiler from sinking the prefetch loads below
        // the compute block (round-2 failure mode).
        asm volatile("" ::: "memory");

        // ---- compute current chunk ----
#pragma unroll
        for (int c = 0; c < CH; c++) {
            const int t = t0 + c;
            if (t >= T) break;
            const float Pt   = buf[cur][c][0];
            const float Tt   = buf[cur][c][1];
            const float PETt = buf[cur][c][2];

            // snow / melt
            const float is_rain = (Tt >= TT) ? 1.0f : 0.0f;
            const float RAIN = Pt * is_rain;
            const float SNOW = Pt - RAIN;
            SP += SNOW;
            const float melt = fminf(fmaxf(CFMAX * (Tt - TT), 0.0f), SP);
            MW += melt; SP -= melt;
            const float refreeze = fminf(fmaxf(CFRCFMAX * (TT - Tt), 0.0f), MW);
            SP += refreeze; MW -= refreeze;
            const float tosoil = fmaxf(MW - CWH * SP, 0.0f);
            MW -= tosoil;

            // soil moisture: SM >= NEARZERO always, so log2 args are > 0.
            const float sw = fminf(__builtin_amdgcn_exp2f(BETA * __builtin_amdgcn_logf(SM * invFC)), 1.0f);
            const float rt = RAIN + tosoil;
            const float recharge = rt * sw;
            SM += rt - recharge;
            const float excess = fmaxf(SM - FC, 0.0f);
            SM -= excess;
            const float ef = fminf(__builtin_amdgcn_exp2f(BETAET * __builtin_amdgcn_logf(SM * invLPFC)), 1.0f);
            const float ETact = fminf(SM, PETt * ef);
            SM = fmaxf(SM - ETact, NEARZERO);
            const float capillary = fminf(SLZ, C * SLZ * (1.0f - fminf(SM * invFC, 1.0f)));
            SM  = fmaxf(SM + capillary, NEARZERO);
            SLZ = fmaxf(SLZ - capillary, NEARZERO);

            // runoff
            SUZ += recharge + excess;
            const float PERC = fminf(SUZ, PERCmax);
            SUZ -= PERC;
            const float Q0 = K0 * fmaxf(SUZ - UZL, 0.0f);
            SUZ -= Q0;
            const float Q1 = K1 * SUZ;
            SUZ -= Q1;
            SLZ += PERC;
            const float Q2 = K2 * SLZ;
            SLZ -= Q2;

            op[(size_t)t * G] = Q0 + Q1 + Q2;
        }
        cur ^= 1;
    }
}

extern "C" void kernel_launch(void* const* d_in, const int* in_sizes, int n_in,
                              void* d_out, int out_size, void* d_ws, size_t ws_size,
                              hipStream_t stream) {
    const float* x   = (const float*)d_in[0];  // (T, G, 3) f32
    const float* par = (const float*)d_in[1];  // (T, G, 14) f32
    float* out = (float*)d_out;                // (T, G) f32

    const int G = 8000;
    const int T = out_size / G;  // 730

    hbv_kernel<<<dim3((G + 63) / 64), dim3(64), 0, stream>>>(x, par, out, T, G);
}